// Round 7
// baseline (308.078 us; speedup 1.0000x reference)
//
#include <hip/hip_runtime.h>

typedef unsigned short u16;
typedef unsigned int u32;
typedef unsigned long long u64;

typedef __bf16 bf16x8 __attribute__((ext_vector_type(8)));
typedef float f32x4 __attribute__((ext_vector_type(4)));
typedef float f32x16 __attribute__((ext_vector_type(16)));

__device__ __forceinline__ float b2f(u16 u) {
    union { u32 i; float f; } c; c.i = ((u32)u) << 16; return c.f;
}
__device__ __forceinline__ u16 f2b(float f) {
    union { float f; u32 i; } c; c.f = f;
    u32 r = c.i + 0x7fffu + ((c.i >> 16) & 1u);
    return (u16)(r >> 16);
}

__device__ __forceinline__ f32x4 mfma16(bf16x8 a, bf16x8 b, f32x4 c) {
    return __builtin_amdgcn_mfma_f32_16x16x32_bf16(a, b, c, 0, 0, 0);
}
__device__ __forceinline__ f32x16 mfma32(bf16x8 a, bf16x8 b, f32x16 c) {
    return __builtin_amdgcn_mfma_f32_32x32x16_bf16(a, b, c, 0, 0, 0);
}

__device__ __forceinline__ void lds_cp16(const u16* gsrc, u16* ldst) {
    __builtin_amdgcn_global_load_lds(
        (const __attribute__((address_space(1))) u32*)gsrc,
        (__attribute__((address_space(3))) u32*)ldst, 16, 0, 0);
}

// ---------------------------------------------------------------------------
// fp32 -> bf16 conversion for the 4 dense weights
// ---------------------------------------------------------------------------
struct ConvJobs {
    const float* s[4];
    u16* d[4];
};

__global__ __launch_bounds__(256) void convert_w(ConvJobs J) {
    int j = blockIdx.y;
    int i = blockIdx.x * 256 + threadIdx.x;  // < 102400
    float4 v = ((const float4*)J.s[j])[i];
    ushort4 o;
    o.x = f2b(v.x); o.y = f2b(v.y); o.z = f2b(v.z); o.w = f2b(v.w);
    ((ushort4*)J.d[j])[i] = o;
}

// ---------------------------------------------------------------------------
// Fused: xb = bf16(x); T[p][m][r] = sum_j x[m][j]*down_p[r][j] (fp32, p=q,k,v)
// ---------------------------------------------------------------------------
__global__ __launch_bounds__(256) void fuse_x(const float* __restrict__ x,
                                              const float* __restrict__ qd,
                                              const float* __restrict__ kd,
                                              const float* __restrict__ vd,
                                              u16* __restrict__ xb,
                                              float* __restrict__ T) {
    int m = blockIdx.x * 4 + (threadIdx.x >> 6);
    int lane = threadIdx.x & 63;
    const float* row = x + (size_t)m * 640;
    u16* orow = xb + (size_t)m * 640;
    float acc[12];
#pragma unroll
    for (int r = 0; r < 12; ++r) acc[r] = 0.f;
#pragma unroll
    for (int ii = 0; ii < 10; ++ii) {
        int i = lane + ii * 64;
        float a = row[i];
        orow[i] = f2b(a);
#pragma unroll
        for (int r = 0; r < 4; ++r) {
            acc[r]     += a * qd[r * 640 + i];
            acc[4 + r] += a * kd[r * 640 + i];
            acc[8 + r] += a * vd[r * 640 + i];
        }
    }
#pragma unroll
    for (int off = 32; off > 0; off >>= 1)
#pragma unroll
        for (int r = 0; r < 12; ++r) acc[r] += __shfl_xor(acc[r], off);
    if (lane == 0) {
#pragma unroll
        for (int p = 0; p < 3; ++p) {
            float4* t = (float4*)(T + ((size_t)p * 8192 + m) * 4);
            *t = make_float4(acc[p * 4], acc[p * 4 + 1], acc[p * 4 + 2], acc[p * 4 + 3]);
        }
    }
}

// ---------------------------------------------------------------------------
// T[m][r] = sum_j A[m][j] * down[r][j]; A bf16, down fp32. (O-proj LoRA down)
// ---------------------------------------------------------------------------
__global__ __launch_bounds__(256) void lora_down_o(const u16* __restrict__ A,
                                                   const float* __restrict__ dn,
                                                   float* __restrict__ T) {
    int m = blockIdx.x * 4 + (threadIdx.x >> 6);
    int lane = threadIdx.x & 63;
    const u16* arow = A + (size_t)m * 640;
    float a0 = 0.f, a1 = 0.f, a2 = 0.f, a3 = 0.f;
    for (int i = lane; i < 640; i += 64) {
        float a = b2f(arow[i]);
        a0 += a * dn[i];
        a1 += a * dn[640 + i];
        a2 += a * dn[1280 + i];
        a3 += a * dn[1920 + i];
    }
#pragma unroll
    for (int off = 32; off > 0; off >>= 1) {
        a0 += __shfl_xor(a0, off);
        a1 += __shfl_xor(a1, off);
        a2 += __shfl_xor(a2, off);
        a3 += __shfl_xor(a3, off);
    }
    if (lane == 0) {
        float4* t = (float4*)(T + (size_t)m * 4);
        *t = make_float4(a0, a1, a2, a3);
    }
}

// ---------------------------------------------------------------------------
// C[m][n] = sum_k A[m][k]*W[n][k] + sum_r T[m][r]*up[n][r] (+bias[n])
// mode 0: out bf16 [B,H,S,hd];  mode 1: out fp32 [M,640] + bias
// ---------------------------------------------------------------------------
struct QkvPtrs {
    const u16* W[3];
    const float* up[3];
    void* out[3];
};

__global__ __launch_bounds__(256) void gemm_bt(const u16* __restrict__ A, QkvPtrs P,
                                               const float* __restrict__ T,
                                               const float* __restrict__ bias, int mode) {
    int z = blockIdx.z;
    const u16* W = P.W[z];
    const float* up = P.up[z];
    const float* Tz = T + (size_t)z * 8192 * 4;
    int m0 = blockIdx.x * 128, n0 = blockIdx.y * 128;
    int tid = threadIdx.x, lane = tid & 63, wid = tid >> 6;
    int g = lane >> 4, l15 = lane & 15;
    __shared__ __align__(16) u16 As[128 * 32];
    __shared__ __align__(16) u16 Bs[128 * 32];
    f32x4 acc[4][4] = {};
    int wm = (wid & 1) * 64, wn = (wid >> 1) * 64;

    for (int k0 = 0; k0 < 640; k0 += 32) {
        __syncthreads();
#pragma unroll
        for (int it = 0; it < 2; ++it) {
            int f = tid + it * 256;
            int r = f >> 2, c = f & 3;
            lds_cp16(A + (size_t)(m0 + r) * 640 + k0 + c * 8, As + f * 8);
            lds_cp16(W + (size_t)(n0 + r) * 640 + k0 + c * 8, Bs + f * 8);
        }
        __syncthreads();
        bf16x8 af[4], bfv[4];
#pragma unroll
        for (int t = 0; t < 4; ++t) {
            af[t] = *(const bf16x8*)(As + (wm + t * 16 + l15) * 32 + g * 8);
            bfv[t] = *(const bf16x8*)(Bs + (wn + t * 16 + l15) * 32 + g * 8);
        }
#pragma unroll
        for (int i = 0; i < 4; ++i)
#pragma unroll
            for (int j = 0; j < 4; ++j)
                acc[i][j] = mfma16(af[i], bfv[j], acc[i][j]);
    }

    float4 upv[4];
    float bv[4];
#pragma unroll
    for (int j = 0; j < 4; ++j) {
        int n = n0 + wn + j * 16 + l15;
        upv[j] = *(const float4*)(up + n * 4);
        bv[j] = mode ? bias[n] : 0.f;
    }
    float* outf = (float*)P.out[z];
    u16* outb = (u16*)P.out[z];
#pragma unroll
    for (int i = 0; i < 4; ++i) {
#pragma unroll
        for (int r = 0; r < 4; ++r) {
            int m = m0 + wm + i * 16 + g * 4 + r;
            const float4 tv = *(const float4*)(Tz + (size_t)m * 4);
#pragma unroll
            for (int j = 0; j < 4; ++j) {
                int n = n0 + wn + j * 16 + l15;
                float v = acc[i][j][r] + tv.x * upv[j].x + tv.y * upv[j].y +
                          tv.z * upv[j].z + tv.w * upv[j].w + bv[j];
                if (mode) {
                    outf[(size_t)m * 640 + n] = v;
                } else {
                    int bb = m >> 11, s = m & 2047;
                    int h = n / 80, d = n - h * 80;
                    outb[(((size_t)bb * 8 + h) * 2048 + s) * 80 + d] = f2b(v);
                }
            }
        }
    }
}

// ---------------------------------------------------------------------------
// V transpose: [B,H,S,80] -> [B,H,96,S] (rows 80=ones, 81..95=0 for l_i trick)
// ---------------------------------------------------------------------------
__global__ __launch_bounds__(256) void transpose_v(const u16* __restrict__ Vin,
                                                   u16* __restrict__ Vout) {
    __shared__ u32 lds32[64 * 41];
    int bh = blockIdx.y;
    int s0 = blockIdx.x * 64;
    int tid = threadIdx.x;
    const u16* in = Vin + (size_t)bh * 2048 * 80;
    u16* out = Vout + (size_t)bh * 96 * 2048;

    for (int t = tid; t < 640; t += 256) {
        int s = t / 10, c = t - s * 10;
        uint4 v = *(const uint4*)(in + (size_t)(s0 + s) * 80 + c * 8);
        u32* p = lds32 + s * 41 + c * 4;
        p[0] = v.x; p[1] = v.y; p[2] = v.z; p[3] = v.w;
    }
    __syncthreads();
    for (int t = tid; t < 640; t += 256) {
        int d = t >> 3, c8 = t & 7;
        int dp = d >> 1, hi = d & 1;
        u16 vals[8];
#pragma unroll
        for (int j = 0; j < 8; ++j) {
            u32 w = lds32[(c8 * 8 + j) * 41 + dp];
            vals[j] = hi ? (u16)(w >> 16) : (u16)(w & 0xffff);
        }
        *(uint4*)(out + (size_t)d * 2048 + s0 + c8 * 8) = *(uint4*)vals;
    }
    // pad rows: 80 = 1.0 (l_i ones column), 81..95 = 0
    for (int t = tid; t < 1024; t += 256) {
        int r = t >> 6, c = t & 63;
        out[(size_t)(80 + r) * 2048 + s0 + c] = (r == 0) ? 0x3F80 : 0;
    }
}

// ---------------------------------------------------------------------------
// Flash attention v5: barrier-free. 32x32x16 MFMA, direct global->reg K/V
// fragment loads (L1-resident tiles), wave-private Ps LDS round-trip only.
// grid (16, 32), 256 threads (4 waves x 32 q-rows).
// ---------------------------------------------------------------------------
__global__ __launch_bounds__(256) void flash_attn(const u16* __restrict__ Q,
                                                  const u16* __restrict__ K,
                                                  const u16* __restrict__ Vt_g,
                                                  u16* __restrict__ O) {
    int bh = blockIdx.y;
    int q0 = blockIdx.x * 128;
    int tid = threadIdx.x;
    int lane = tid & 63, wid = tid >> 6, l31 = lane & 31, h2 = lane >> 5;
    const size_t base = (size_t)bh * 2048 * 80;      // Q,K [B,H,S,80]
    const size_t vbase = (size_t)bh * 96 * 2048;     // Vt [B,H,96,S]

    __shared__ __align__(16) u16 Ps[4 * 32 * 72];    // per wave: [32 q][64 key pad 72]

    // Q fragments: B[n=l31 q][k=h2*8+j], 5 k-slices of 16
    bf16x8 qf[5];
    {
        int qrow = q0 + wid * 32 + l31;
#pragma unroll
        for (int ks = 0; ks < 5; ++ks)
            qf[ks] = *(const bf16x8*)(Q + base + (size_t)qrow * 80 + ks * 16 + h2 * 8);
    }

    f32x16 oa[3] = {};
    const float sm_scale = 0.11180339887498949f;  // 1/sqrt(80)
    const float SHIFT = 12.0f;
    int wb = wid * 2304;  // 32*72 per wave

    for (int kt = 0; kt < 2048; kt += 64) {
        // S^T = K·Q^T: A-frag loaded straight from global (row = key)
        f32x16 sc[2];
#pragma unroll
        for (int kk2 = 0; kk2 < 2; ++kk2) {
            f32x16 s = {};
#pragma unroll
            for (int ks = 0; ks < 5; ++ks) {
                bf16x8 kf = *(const bf16x8*)(K + base +
                    (size_t)(kt + kk2 * 32 + l31) * 80 + ks * 16 + h2 * 8);
                s = mfma32(kf, qf[ks], s);
            }
            sc[kk2] = s;
        }

        // exp (fixed shift) -> packed b64 writes (wave-private Ps)
#pragma unroll
        for (int kk2 = 0; kk2 < 2; ++kk2)
#pragma unroll
            for (int rg = 0; rg < 4; ++rg) {
                u64 pk = (u64)f2b(__expf(sc[kk2][rg * 4 + 0] * sm_scale - SHIFT)) |
                         ((u64)f2b(__expf(sc[kk2][rg * 4 + 1] * sm_scale - SHIFT)) << 16) |
                         ((u64)f2b(__expf(sc[kk2][rg * 4 + 2] * sm_scale - SHIFT)) << 32) |
                         ((u64)f2b(__expf(sc[kk2][rg * 4 + 3] * sm_scale - SHIFT)) << 48);
                *(u64*)(Ps + wb + l31 * 72 + kk2 * 32 + rg * 8 + h2 * 4) = pk;
            }

        // PV: A=P[q=l31][key] from LDS, B=V[vd=l31][key] straight from global
        bf16x8 pf[4];
#pragma unroll
        for (int ks16 = 0; ks16 < 4; ++ks16)
            pf[ks16] = *(const bf16x8*)(Ps + wb + l31 * 72 + ks16 * 16 + h2 * 8);
#pragma unroll
        for (int nt = 0; nt < 3; ++nt)
#pragma unroll
            for (int ks16 = 0; ks16 < 4; ++ks16) {
                bf16x8 vf = *(const bf16x8*)(Vt_g + vbase +
                    (size_t)(nt * 32 + l31) * 2048 + kt + ks16 * 16 + h2 * 8);
                oa[nt] = mfma32(pf[ks16], vf, oa[nt]);
            }
    }

    // epilogue: l_i lives in oa[2] col 16 (vd=80 ones column)
    int b = bh >> 3, h = bh & 7;
    float inv[16];
#pragma unroll
    for (int reg = 0; reg < 16; ++reg)
        inv[reg] = 1.f / __shfl(oa[2][reg], (lane & 32) + 16, 64);
#pragma unroll
    for (int nt = 0; nt < 3; ++nt) {
        int vd = nt * 32 + l31;
        if (vd < 80) {
#pragma unroll
            for (int reg = 0; reg < 16; ++reg) {
                int q = q0 + wid * 32 + (reg & 3) + 8 * (reg >> 2) + 4 * h2;
                O[((size_t)(b * 2048 + q)) * 640 + h * 80 + vd] = f2b(oa[nt][reg] * inv[reg]);
            }
        }
    }
}

// ---------------------------------------------------------------------------
extern "C" void kernel_launch(void* const* d_in, const int* in_sizes, int n_in,
                              void* d_out, int out_size, void* d_ws, size_t ws_size,
                              hipStream_t stream) {
    const float* x      = (const float*)d_in[0];
    const float* wq     = (const float*)d_in[1];
    const float* wk     = (const float*)d_in[2];
    const float* wv     = (const float*)d_in[3];
    const float* wo     = (const float*)d_in[4];
    const float* bo     = (const float*)d_in[5];
    const float* q_down = (const float*)d_in[6];
    const float* q_up   = (const float*)d_in[7];
    const float* k_down = (const float*)d_in[8];
    const float* k_up   = (const float*)d_in[9];
    const float* v_down = (const float*)d_in[10];
    const float* v_up   = (const float*)d_in[11];
    const float* o_down = (const float*)d_in[12];
    const float* o_up   = (const float*)d_in[13];

    char* ws = (char*)d_ws;
    u16* xb    = (u16*)(ws);                  // [8192][640] bf16 (dead after gemmQKV)
    u16* vT_ws = (u16*)(ws);                  // [B,H,96,S] 12,582,912 B — overlaps
                                              // xb + wbv + wbq + part of wbk (all dead
                                              // after gemm QKV, which precedes transpose_v)
    u16* wbv   = (u16*)(ws + 10485760);       // [640][640] bf16 each
    u16* wbq   = (u16*)(ws + 11304960);
    u16* wbk   = (u16*)(ws + 12124160);
    u16* wbo   = (u16*)(ws + 12943360);       // survives (beyond vT end 12,582,912)
    u16* q_ws  = (u16*)(ws + 13762560);       // [B,H,S,80] bf16
    u16* k_ws  = (u16*)(ws + 24248320);       // [B,H,S,80]
    u16* v_ws  = (u16*)(ws + 34734080);       // [B,H,S,80] natural
    u16* attn  = (u16*)(ws + 45219840);       // [B*S][640] bf16
    float* Tq  = (float*)(ws + 55705600);     // [3][8192][4] fp32
    float* To  = (float*)(ws + 56098816);     // [8192][4] fp32

    // 0) weights fp32 -> bf16
    ConvJobs cj;
    cj.s[0] = wq; cj.d[0] = wbq;
    cj.s[1] = wk; cj.d[1] = wbk;
    cj.s[2] = wv; cj.d[2] = wbv;
    cj.s[3] = wo; cj.d[3] = wbo;
    convert_w<<<dim3(400, 4), 256, 0, stream>>>(cj);

    // 1) fused x convert + QKV LoRA down
    fuse_x<<<2048, 256, 0, stream>>>(x, q_down, k_down, v_down, xb, Tq);

    // 2) QKV projections (+LoRA up) -> [B,H,S,80] bf16
    QkvPtrs pq;
    pq.W[0] = wbq; pq.W[1] = wbk; pq.W[2] = wbv;
    pq.up[0] = q_up; pq.up[1] = k_up; pq.up[2] = v_up;
    pq.out[0] = q_ws; pq.out[1] = k_ws; pq.out[2] = v_ws;
    gemm_bt<<<dim3(64, 5, 3), 256, 0, stream>>>(xb, pq, Tq, bo, 0);

    // 3) V transpose -> [B,H,96,S] with ones row 80 (overwrites dead regions)
    transpose_v<<<dim3(32, 32), 256, 0, stream>>>(v_ws, vT_ws);

    // 4) attention (barrier-free) -> token-major bf16
    flash_attn<<<dim3(16, 32), 256, 0, stream>>>(q_ws, k_ws, vT_ws, attn);

    // 5) O-proj LoRA down
    lora_down_o<<<2048, 256, 0, stream>>>(attn, o_down, To);

    // 6) O projection (+bias +LoRA up) -> fp32 d_out
    QkvPtrs po;
    po.W[0] = wbo; po.W[1] = wbo; po.W[2] = wbo;
    po.up[0] = o_up; po.up[1] = o_up; po.up[2] = o_up;
    po.out[0] = d_out; po.out[1] = d_out; po.out[2] = d_out;
    gemm_bt<<<dim3(64, 5, 1), 256, 0, stream>>>(attn, po, To, bo, 1);
}

// Round 8
// 252.531 us; speedup vs baseline: 1.2200x; 1.2200x over previous
//
#include <hip/hip_runtime.h>

typedef unsigned short u16;
typedef unsigned int u32;
typedef unsigned long long u64;

typedef __bf16 bf16x8 __attribute__((ext_vector_type(8)));
typedef float f32x4 __attribute__((ext_vector_type(4)));
typedef float f32x16 __attribute__((ext_vector_type(16)));

__device__ __forceinline__ float b2f(u16 u) {
    union { u32 i; float f; } c; c.i = ((u32)u) << 16; return c.f;
}
__device__ __forceinline__ u16 f2b(float f) {
    union { float f; u32 i; } c; c.f = f;
    u32 r = c.i + 0x7fffu + ((c.i >> 16) & 1u);
    return (u16)(r >> 16);
}
__device__ __forceinline__ u32 pack2(float a, float b) {
    return (u32)f2b(a) | ((u32)f2b(b) << 16);
}

__device__ __forceinline__ f32x4 mfma16(bf16x8 a, bf16x8 b, f32x4 c) {
    return __builtin_amdgcn_mfma_f32_16x16x32_bf16(a, b, c, 0, 0, 0);
}
__device__ __forceinline__ f32x16 mfma32(bf16x8 a, bf16x8 b, f32x16 c) {
    return __builtin_amdgcn_mfma_f32_32x32x16_bf16(a, b, c, 0, 0, 0);
}

__device__ __forceinline__ void lds_cp16(const u16* gsrc, u16* ldst) {
    __builtin_amdgcn_global_load_lds(
        (const __attribute__((address_space(1))) u32*)gsrc,
        (__attribute__((address_space(3))) u32*)ldst, 16, 0, 0);
}

// ---------------------------------------------------------------------------
// fp32 -> bf16 conversion for the 4 dense weights
// ---------------------------------------------------------------------------
struct ConvJobs {
    const float* s[4];
    u16* d[4];
};

__global__ __launch_bounds__(256) void convert_w(ConvJobs J) {
    int j = blockIdx.y;
    int i = blockIdx.x * 256 + threadIdx.x;  // < 102400
    float4 v = ((const float4*)J.s[j])[i];
    ushort4 o;
    o.x = f2b(v.x); o.y = f2b(v.y); o.z = f2b(v.z); o.w = f2b(v.w);
    ((ushort4*)J.d[j])[i] = o;
}

// ---------------------------------------------------------------------------
// Fused: xb = bf16(x); T[p][m][r] = sum_j x[m][j]*down_p[r][j] (fp32, p=q,k,v)
// ---------------------------------------------------------------------------
__global__ __launch_bounds__(256) void fuse_x(const float* __restrict__ x,
                                              const float* __restrict__ qd,
                                              const float* __restrict__ kd,
                                              const float* __restrict__ vd,
                                              u16* __restrict__ xb,
                                              float* __restrict__ T) {
    int m = blockIdx.x * 4 + (threadIdx.x >> 6);
    int lane = threadIdx.x & 63;
    const float* row = x + (size_t)m * 640;
    u16* orow = xb + (size_t)m * 640;
    float acc[12];
#pragma unroll
    for (int r = 0; r < 12; ++r) acc[r] = 0.f;
#pragma unroll
    for (int ii = 0; ii < 10; ++ii) {
        int i = lane + ii * 64;
        float a = row[i];
        orow[i] = f2b(a);
#pragma unroll
        for (int r = 0; r < 4; ++r) {
            acc[r]     += a * qd[r * 640 + i];
            acc[4 + r] += a * kd[r * 640 + i];
            acc[8 + r] += a * vd[r * 640 + i];
        }
    }
#pragma unroll
    for (int off = 32; off > 0; off >>= 1)
#pragma unroll
        for (int r = 0; r < 12; ++r) acc[r] += __shfl_xor(acc[r], off);
    if (lane == 0) {
#pragma unroll
        for (int p = 0; p < 3; ++p) {
            float4* t = (float4*)(T + ((size_t)p * 8192 + m) * 4);
            *t = make_float4(acc[p * 4], acc[p * 4 + 1], acc[p * 4 + 2], acc[p * 4 + 3]);
        }
    }
}

// ---------------------------------------------------------------------------
// T[m][r] = sum_j A[m][j] * down[r][j]; A bf16, down fp32. (O-proj LoRA down)
// ---------------------------------------------------------------------------
__global__ __launch_bounds__(256) void lora_down_o(const u16* __restrict__ A,
                                                   const float* __restrict__ dn,
                                                   float* __restrict__ T) {
    int m = blockIdx.x * 4 + (threadIdx.x >> 6);
    int lane = threadIdx.x & 63;
    const u16* arow = A + (size_t)m * 640;
    float a0 = 0.f, a1 = 0.f, a2 = 0.f, a3 = 0.f;
    for (int i = lane; i < 640; i += 64) {
        float a = b2f(arow[i]);
        a0 += a * dn[i];
        a1 += a * dn[640 + i];
        a2 += a * dn[1280 + i];
        a3 += a * dn[1920 + i];
    }
#pragma unroll
    for (int off = 32; off > 0; off >>= 1) {
        a0 += __shfl_xor(a0, off);
        a1 += __shfl_xor(a1, off);
        a2 += __shfl_xor(a2, off);
        a3 += __shfl_xor(a3, off);
    }
    if (lane == 0) {
        float4* t = (float4*)(T + (size_t)m * 4);
        *t = make_float4(a0, a1, a2, a3);
    }
}

// ---------------------------------------------------------------------------
// C[m][n] = sum_k A[m][k]*W[n][k] + sum_r T[m][r]*up[n][r] (+bias[n])
// mode 0: out bf16 [B,H,S,hd];  mode 1: out fp32 [M,640] + bias
// ---------------------------------------------------------------------------
struct QkvPtrs {
    const u16* W[3];
    const float* up[3];
    void* out[3];
};

__global__ __launch_bounds__(256) void gemm_bt(const u16* __restrict__ A, QkvPtrs P,
                                               const float* __restrict__ T,
                                               const float* __restrict__ bias, int mode) {
    int z = blockIdx.z;
    const u16* W = P.W[z];
    const float* up = P.up[z];
    const float* Tz = T + (size_t)z * 8192 * 4;
    int m0 = blockIdx.x * 128, n0 = blockIdx.y * 128;
    int tid = threadIdx.x, lane = tid & 63, wid = tid >> 6;
    int g = lane >> 4, l15 = lane & 15;
    __shared__ __align__(16) u16 As[128 * 32];
    __shared__ __align__(16) u16 Bs[128 * 32];
    f32x4 acc[4][4] = {};
    int wm = (wid & 1) * 64, wn = (wid >> 1) * 64;

    for (int k0 = 0; k0 < 640; k0 += 32) {
        __syncthreads();
#pragma unroll
        for (int it = 0; it < 2; ++it) {
            int f = tid + it * 256;
            int r = f >> 2, c = f & 3;
            lds_cp16(A + (size_t)(m0 + r) * 640 + k0 + c * 8, As + f * 8);
            lds_cp16(W + (size_t)(n0 + r) * 640 + k0 + c * 8, Bs + f * 8);
        }
        __syncthreads();
        bf16x8 af[4], bfv[4];
#pragma unroll
        for (int t = 0; t < 4; ++t) {
            af[t] = *(const bf16x8*)(As + (wm + t * 16 + l15) * 32 + g * 8);
            bfv[t] = *(const bf16x8*)(Bs + (wn + t * 16 + l15) * 32 + g * 8);
        }
#pragma unroll
        for (int i = 0; i < 4; ++i)
#pragma unroll
            for (int j = 0; j < 4; ++j)
                acc[i][j] = mfma16(af[i], bfv[j], acc[i][j]);
    }

    float4 upv[4];
    float bv[4];
#pragma unroll
    for (int j = 0; j < 4; ++j) {
        int n = n0 + wn + j * 16 + l15;
        upv[j] = *(const float4*)(up + n * 4);
        bv[j] = mode ? bias[n] : 0.f;
    }
    float* outf = (float*)P.out[z];
    u16* outb = (u16*)P.out[z];
#pragma unroll
    for (int i = 0; i < 4; ++i) {
#pragma unroll
        for (int r = 0; r < 4; ++r) {
            int m = m0 + wm + i * 16 + g * 4 + r;
            const float4 tv = *(const float4*)(Tz + (size_t)m * 4);
#pragma unroll
            for (int j = 0; j < 4; ++j) {
                int n = n0 + wn + j * 16 + l15;
                float v = acc[i][j][r] + tv.x * upv[j].x + tv.y * upv[j].y +
                          tv.z * upv[j].z + tv.w * upv[j].w + bv[j];
                if (mode) {
                    outf[(size_t)m * 640 + n] = v;
                } else {
                    int bb = m >> 11, s = m & 2047;
                    int h = n / 80, d = n - h * 80;
                    outb[(((size_t)bb * 8 + h) * 2048 + s) * 80 + d] = f2b(v);
                }
            }
        }
    }
}

// ---------------------------------------------------------------------------
// V transpose: [B,H,S,80] -> [B,H,96,S] (rows 80=ones, 81..95=0 for l_i trick)
// ---------------------------------------------------------------------------
__global__ __launch_bounds__(256) void transpose_v(const u16* __restrict__ Vin,
                                                   u16* __restrict__ Vout) {
    __shared__ u32 lds32[64 * 41];
    int bh = blockIdx.y;
    int s0 = blockIdx.x * 64;
    int tid = threadIdx.x;
    const u16* in = Vin + (size_t)bh * 2048 * 80;
    u16* out = Vout + (size_t)bh * 96 * 2048;

    for (int t = tid; t < 640; t += 256) {
        int s = t / 10, c = t - s * 10;
        uint4 v = *(const uint4*)(in + (size_t)(s0 + s) * 80 + c * 8);
        u32* p = lds32 + s * 41 + c * 4;
        p[0] = v.x; p[1] = v.y; p[2] = v.z; p[3] = v.w;
    }
    __syncthreads();
    for (int t = tid; t < 640; t += 256) {
        int d = t >> 3, c8 = t & 7;
        int dp = d >> 1, hi = d & 1;
        u16 vals[8];
#pragma unroll
        for (int j = 0; j < 8; ++j) {
            u32 w = lds32[(c8 * 8 + j) * 41 + dp];
            vals[j] = hi ? (u16)(w >> 16) : (u16)(w & 0xffff);
        }
        *(uint4*)(out + (size_t)d * 2048 + s0 + c8 * 8) = *(uint4*)vals;
    }
    // pad rows: 80 = 1.0 (l_i ones column), 81..95 = 0
    for (int t = tid; t < 1024; t += 256) {
        int r = t >> 6, c = t & 63;
        out[(size_t)(80 + r) * 2048 + s0 + c] = (r == 0) ? 0x3F80 : 0;
    }
}

// ---------------------------------------------------------------------------
// Flash attention v6: S^T MFMA + in-register P transform (shfl_xor 32),
// double-buffered LDS staging, ONE barrier per K-tile.
// grid (8, 32), 512 threads (8 waves x 32 q-rows).
// Q,K: [B,H,S,80]; Vt_g: [B,H,96,S] (row 80 = ones -> l_i for free).
// ---------------------------------------------------------------------------
__global__ __launch_bounds__(512) void flash_attn(const u16* __restrict__ Q,
                                                  const u16* __restrict__ K,
                                                  const u16* __restrict__ Vt_g,
                                                  u16* __restrict__ O) {
    int bh = blockIdx.y;
    int q0 = blockIdx.x * 256;
    int tid = threadIdx.x;
    int lane = tid & 63, wid = tid >> 6, l31 = lane & 31, h2 = lane >> 5;
    const size_t base = (size_t)bh * 2048 * 80;     // Q,K
    const size_t vbase = (size_t)bh * 96 * 2048;    // Vt_g

    // dbuf: Ks[2][64*88] u16 (11264B each as 704 chunks of 16B),
    //       Vt[2][100*72] u16 (14400B each as 900 chunks; stage 896, pad)
    __shared__ __align__(16) u16 lds[2 * 5632 + 2 * 7200];
    u16* Ks0 = lds;
    u16* Vt0 = lds + 11264;

    // Q fragments: B[n=l31 q][k=h2*8+j], 5 k-slices of 16
    bf16x8 qf[5];
    {
        int qrow = q0 + wid * 32 + l31;
#pragma unroll
        for (int ks = 0; ks < 5; ++ks)
            qf[ks] = *(const bf16x8*)(Q + base + (size_t)qrow * 80 + ks * 16 + h2 * 8);
    }

    f32x16 oa[3] = {};
    const float sm_scale = 0.11180339887498949f;  // 1/sqrt(80)
    const float SHIFT = 12.0f;

    // flat-chunk staging: chunks 0..703 -> Ks (row=c/11, col16=c%11),
    // 704..1599 -> Vt rows 0..99 (row=(c-704)/9, col16=(c-704)%9). 25 waves.
    auto stage = [&](int buf, int kt) {
#pragma unroll
        for (int it = 0; it < 4; ++it) {
            int c = tid + it * 512;
            if (c < 704) {
                int row = c / 11, col = c - row * 11;
                lds_cp16(K + base + (size_t)(kt + row) * 80 + col * 8,
                         Ks0 + buf * 5632 + c * 8);
            } else if (c < 1600) {
                int t = c - 704;
                int row = t / 9, col = t - row * 9;
                lds_cp16(Vt_g + vbase + (size_t)row * 2048 + kt + col * 8,
                         Vt0 + buf * 7200 + t * 8);
            }
        }
    };

    stage(0, 0);
    __syncthreads();

    for (int i = 0; i < 32; ++i) {
        int cur = i & 1;
        if (i < 31) stage(cur ^ 1, (i + 1) * 64);

        const u16* ks = Ks0 + cur * 5632;
        const u16* vt = Vt0 + cur * 7200;

#pragma unroll
        for (int kk2 = 0; kk2 < 2; ++kk2) {
            // S^T = K·Q^T: lane -> q-col=l31, key-row=(reg&3)+8*(reg>>2)+4*h2+32*kk2
            f32x16 s = {};
#pragma unroll
            for (int ks5 = 0; ks5 < 5; ++ks5) {
                bf16x8 kf = *(const bf16x8*)(ks + (kk2 * 32 + l31) * 88 + ks5 * 16 + h2 * 8);
                s = mfma32(kf, qf[ks5], s);
            }
            // exp + pack pairs: d[j] = keys 8*(j>>1) + 4*h2 + 2*(j&1) + {0,1}
            u32 d[8], e[8];
#pragma unroll
            for (int j = 0; j < 8; ++j)
                d[j] = pack2(__expf(s[2 * j] * sm_scale - SHIFT),
                             __expf(s[2 * j + 1] * sm_scale - SHIFT));
#pragma unroll
            for (int j = 0; j < 8; ++j) e[j] = __shfl_xor(d[j], 32);
            // PV over the 32 staged keys of this kk2, as two 16-key slices
#pragma unroll
            for (int sl = 0; sl < 2; ++sl) {
                union { u32 w[4]; bf16x8 v; } pa;
                pa.w[0] = h2 ? e[4 * sl + 2] : d[4 * sl + 0];
                pa.w[1] = h2 ? e[4 * sl + 3] : d[4 * sl + 1];
                pa.w[2] = h2 ? d[4 * sl + 2] : e[4 * sl + 0];
                pa.w[3] = h2 ? d[4 * sl + 3] : e[4 * sl + 1];
#pragma unroll
                for (int nt = 0; nt < 3; ++nt) {
                    bf16x8 vf = *(const bf16x8*)(vt + (nt * 32 + l31) * 72 +
                                                 kk2 * 32 + sl * 16 + h2 * 8);
                    oa[nt] = mfma32(pa.v, vf, oa[nt]);
                }
            }
        }
        __syncthreads();
    }

    // epilogue: l_i lives in oa[2] col 16 (vd=80 ones column)
    int b = bh >> 3, h = bh & 7;
    float inv[16];
#pragma unroll
    for (int reg = 0; reg < 16; ++reg)
        inv[reg] = 1.f / __shfl(oa[2][reg], (lane & 32) + 16, 64);
#pragma unroll
    for (int nt = 0; nt < 3; ++nt) {
        int vd = nt * 32 + l31;
        if (vd < 80) {
#pragma unroll
            for (int reg = 0; reg < 16; ++reg) {
                int q = q0 + wid * 32 + (reg & 3) + 8 * (reg >> 2) + 4 * h2;
                O[((size_t)(b * 2048 + q)) * 640 + h * 80 + vd] = f2b(oa[nt][reg] * inv[reg]);
            }
        }
    }
}

// ---------------------------------------------------------------------------
extern "C" void kernel_launch(void* const* d_in, const int* in_sizes, int n_in,
                              void* d_out, int out_size, void* d_ws, size_t ws_size,
                              hipStream_t stream) {
    const float* x      = (const float*)d_in[0];
    const float* wq     = (const float*)d_in[1];
    const float* wk     = (const float*)d_in[2];
    const float* wv     = (const float*)d_in[3];
    const float* wo     = (const float*)d_in[4];
    const float* bo     = (const float*)d_in[5];
    const float* q_down = (const float*)d_in[6];
    const float* q_up   = (const float*)d_in[7];
    const float* k_down = (const float*)d_in[8];
    const float* k_up   = (const float*)d_in[9];
    const float* v_down = (const float*)d_in[10];
    const float* v_up   = (const float*)d_in[11];
    const float* o_down = (const float*)d_in[12];
    const float* o_up   = (const float*)d_in[13];

    char* ws = (char*)d_ws;
    u16* xb    = (u16*)(ws);                  // [8192][640] bf16 (dead after gemmQKV)
    u16* vT_ws = (u16*)(ws);                  // [B,H,96,S] 12,582,912 B — overlaps
                                              // xb/wbv/wbq/part-of-wbk (dead by then)
    u16* wbv   = (u16*)(ws + 10485760);
    u16* wbq   = (u16*)(ws + 11304960);
    u16* wbk   = (u16*)(ws + 12124160);
    u16* wbo   = (u16*)(ws + 12943360);       // survives (beyond vT end 12,582,912)
    u16* q_ws  = (u16*)(ws + 13762560);       // [B,H,S,80] bf16
    u16* k_ws  = (u16*)(ws + 24248320);       // [B,H,S,80]
    u16* v_ws  = (u16*)(ws + 34734080);       // [B,H,S,80] natural
    u16* attn  = (u16*)(ws + 45219840);       // [B*S][640] bf16
    float* Tq  = (float*)(ws + 55705600);     // [3][8192][4] fp32
    float* To  = (float*)(ws + 56098816);     // [8192][4] fp32

    // 0) weights fp32 -> bf16
    ConvJobs cj;
    cj.s[0] = wq; cj.d[0] = wbq;
    cj.s[1] = wk; cj.d[1] = wbk;
    cj.s[2] = wv; cj.d[2] = wbv;
    cj.s[3] = wo; cj.d[3] = wbo;
    convert_w<<<dim3(400, 4), 256, 0, stream>>>(cj);

    // 1) fused x convert + QKV LoRA down
    fuse_x<<<2048, 256, 0, stream>>>(x, q_down, k_down, v_down, xb, Tq);

    // 2) QKV projections (+LoRA up) -> [B,H,S,80] bf16
    QkvPtrs pq;
    pq.W[0] = wbq; pq.W[1] = wbk; pq.W[2] = wbv;
    pq.up[0] = q_up; pq.up[1] = k_up; pq.up[2] = v_up;
    pq.out[0] = q_ws; pq.out[1] = k_ws; pq.out[2] = v_ws;
    gemm_bt<<<dim3(64, 5, 3), 256, 0, stream>>>(xb, pq, Tq, bo, 0);

    // 3) V transpose -> [B,H,96,S] with ones row 80
    transpose_v<<<dim3(32, 32), 256, 0, stream>>>(v_ws, vT_ws);

    // 4) attention (dbuf, 1 barrier/tile) -> token-major bf16
    flash_attn<<<dim3(8, 32), 512, 0, stream>>>(q_ws, k_ws, vT_ws, attn);

    // 5) O-proj LoRA down
    lora_down_o<<<2048, 256, 0, stream>>>(attn, o_down, To);

    // 6) O projection (+bias +LoRA up) -> fp32 d_out
    QkvPtrs po;
    po.W[0] = wbo; po.W[1] = wbo; po.W[2] = wbo;
    po.up[0] = o_up; po.up[1] = o_up; po.up[2] = o_up;
    po.out[0] = d_out; po.out[1] = d_out; po.out[2] = d_out;
    gemm_bt<<<dim3(64, 5, 1), 256, 0, stream>>>(attn, po, To, bo, 1);
}